// Round 1
// baseline (341.277 us; speedup 1.0000x reference)
//
#include <hip/hip_runtime.h>
#include <math.h>

#define NN 50000
#define KK 16
#define FIN 140
#define HH 8
#define DD 16
#define HID 128
#define NPB 8   // nodes per block in the matmul kernels

// x = relu(feature @ pca_w + pca_b)   [N,140]@[140,128]
__global__ __launch_bounds__(128) void pca_kernel(
    const float* __restrict__ feat, const float* __restrict__ w,
    const float* __restrict__ b, float* __restrict__ x) {
  const int n0 = blockIdx.x * NPB;
  const int j = threadIdx.x;            // output column
  __shared__ float fr[NPB * FIN];
  const float* fbase = feat + (size_t)n0 * FIN;
  for (int t = j; t < NPB * FIN; t += 128) fr[t] = fbase[t];
  __syncthreads();
  float acc[NPB];
  const float bj = b[j];
#pragma unroll
  for (int p = 0; p < NPB; ++p) acc[p] = bj;
  for (int i = 0; i < FIN; i += 4) {    // 140 = 4*35
    const float w0 = w[(i + 0) * HID + j];
    const float w1 = w[(i + 1) * HID + j];
    const float w2 = w[(i + 2) * HID + j];
    const float w3 = w[(i + 3) * HID + j];
#pragma unroll
    for (int p = 0; p < NPB; ++p) {
      const float* fp = &fr[p * FIN + i];
      acc[p] = fmaf(fp[0], w0, acc[p]);
      acc[p] = fmaf(fp[1], w1, acc[p]);
      acc[p] = fmaf(fp[2], w2, acc[p]);
      acc[p] = fmaf(fp[3], w3, acc[p]);
    }
  }
#pragma unroll
  for (int p = 0; p < NPB; ++p)
    x[(size_t)(n0 + p) * HID + j] = fmaxf(acc[p], 0.f);
}

// h = x@W + b ; s_src = <h, a_src> per head ; s_dst = <h, a_dst> per head
__global__ __launch_bounds__(128) void proj_kernel(
    const float* __restrict__ x, const float* __restrict__ W,
    const float* __restrict__ b, const float* __restrict__ asrc,
    const float* __restrict__ adst, float* __restrict__ h,
    float* __restrict__ ssrc, float* __restrict__ sdst) {
  const int n0 = blockIdx.x * NPB;
  const int j = threadIdx.x;            // output column = head*16 + d
  __shared__ float xr[NPB * HID];
  const float* xbase = x + (size_t)n0 * HID;
  for (int t = j; t < NPB * HID; t += 128) xr[t] = xbase[t];
  __syncthreads();
  float acc[NPB];
  const float bj = b[j];
#pragma unroll
  for (int p = 0; p < NPB; ++p) acc[p] = bj;
  for (int i = 0; i < HID; i += 4) {
    const float w0 = W[(i + 0) * HID + j];
    const float w1 = W[(i + 1) * HID + j];
    const float w2 = W[(i + 2) * HID + j];
    const float w3 = W[(i + 3) * HID + j];
#pragma unroll
    for (int p = 0; p < NPB; ++p) {
      const float4 xv = *(const float4*)&xr[p * HID + i];
      acc[p] = fmaf(xv.x, w0, acc[p]);
      acc[p] = fmaf(xv.y, w1, acc[p]);
      acc[p] = fmaf(xv.z, w2, acc[p]);
      acc[p] = fmaf(xv.w, w3, acc[p]);
    }
  }
  const float av = asrc[j];
  const float dv = adst[j];
  const int head = j >> 4;              // d = j & 15
#pragma unroll
  for (int p = 0; p < NPB; ++p) {
    h[(size_t)(n0 + p) * HID + j] = acc[p];
    float vs = acc[p] * av;
    float vd = acc[p] * dv;
    vs += __shfl_xor(vs, 1, 16); vd += __shfl_xor(vd, 1, 16);
    vs += __shfl_xor(vs, 2, 16); vd += __shfl_xor(vd, 2, 16);
    vs += __shfl_xor(vs, 4, 16); vd += __shfl_xor(vd, 4, 16);
    vs += __shfl_xor(vs, 8, 16); vd += __shfl_xor(vd, 8, 16);
    if ((j & 15) == 0) {
      ssrc[(size_t)(n0 + p) * HH + head] = vs;
      sdst[(size_t)(n0 + p) * HH + head] = vd;
    }
  }
}

// per node: e[k,h] = leaky(s_src[n,h] + s_dst[nb[k],h]); softmax over k;
// out[h,d] = sum_k alpha[k,h]*h[nb[k],h,d]; x = elu(out)
__global__ __launch_bounds__(128) void attn_kernel(
    const int* __restrict__ nb, const float* __restrict__ h,
    const float* __restrict__ ssrc, const float* __restrict__ sdst,
    float* __restrict__ xout) {
  const int n = blockIdx.x;
  const int j = threadIdx.x;
  __shared__ int nbs[KK];
  __shared__ float aw[KK][HH];
  if (j < KK) nbs[j] = nb[(size_t)n * KK + j];
  __syncthreads();
  {
    const int k = j >> 3, hh = j & 7;   // 128 threads = 16 k * 8 h
    float e = ssrc[(size_t)n * HH + hh] + sdst[(size_t)nbs[k] * HH + hh];
    e = e > 0.f ? e : 0.2f * e;
    aw[k][hh] = e;
  }
  __syncthreads();
  if (j < HH) {                         // softmax over K for head j
    float m = -1e30f;
#pragma unroll
    for (int k = 0; k < KK; ++k) m = fmaxf(m, aw[k][j]);
    float s = 0.f;
#pragma unroll
    for (int k = 0; k < KK; ++k) {
      const float v = __expf(aw[k][j] - m);
      aw[k][j] = v;
      s += v;
    }
    const float inv = 1.f / s;
#pragma unroll
    for (int k = 0; k < KK; ++k) aw[k][j] *= inv;
  }
  __syncthreads();
  const int head = j >> 4;
  float acc = 0.f;
#pragma unroll
  for (int k = 0; k < KK; ++k)
    acc = fmaf(aw[k][head], h[(size_t)nbs[k] * HID + j], acc);
  xout[(size_t)n * HID + j] = acc > 0.f ? acc : expm1f(acc);
}

extern "C" void kernel_launch(void* const* d_in, const int* in_sizes, int n_in,
                              void* d_out, int out_size, void* d_ws, size_t ws_size,
                              hipStream_t stream) {
  const float* feature = (const float*)d_in[0];
  const int*   nb      = (const int*)d_in[1];
  const float* pca_w   = (const float*)d_in[2];
  const float* pca_b   = (const float*)d_in[3];
  const float* Ws      = (const float*)d_in[4];
  const float* bs      = (const float*)d_in[5];
  const float* a_src   = (const float*)d_in[6];
  const float* a_dst   = (const float*)d_in[7];
  float* out = (float*)d_out;

  float* xbuf = (float*)d_ws;                       // [N,128]
  float* hbuf = xbuf + (size_t)NN * HID;            // [N,128]
  float* ssrc = hbuf + (size_t)NN * HID;            // [N,8]
  float* sdst = ssrc + (size_t)NN * HH;             // [N,8]

  pca_kernel<<<NN / NPB, 128, 0, stream>>>(feature, pca_w, pca_b, xbuf);
  for (int l = 0; l < 2; ++l) {
    proj_kernel<<<NN / NPB, 128, 0, stream>>>(
        xbuf, Ws + (size_t)l * HID * HID, bs + (size_t)l * HID,
        a_src + (size_t)l * HID, a_dst + (size_t)l * HID, hbuf, ssrc, sdst);
    attn_kernel<<<NN, 128, 0, stream>>>(nb, hbuf, ssrc, sdst,
                                        (l == 1) ? out : xbuf);
  }
}

// Round 2
// 284.469 us; speedup vs baseline: 1.1997x; 1.1997x over previous
//
#include <hip/hip_runtime.h>
#include <hip/hip_bf16.h>
#include <math.h>

#define NN 50000
#define KK 16
#define FIN 140
#define HH 8
#define DD 16
#define HID 128
#define NPB 16   // nodes per block in the matmul kernels (50000/16 = 3125)

// x = relu(feature @ pca_w + pca_b)   [N,140]@[140,128]
__global__ __launch_bounds__(128) void pca_kernel(
    const float* __restrict__ feat, const float* __restrict__ w,
    const float* __restrict__ b, float* __restrict__ x) {
  const int n0 = blockIdx.x * NPB;
  const int j = threadIdx.x;            // output column
  __shared__ float fr[NPB * FIN];
  const float* fbase = feat + (size_t)n0 * FIN;
  for (int t = j; t < NPB * FIN; t += 128) fr[t] = fbase[t];
  __syncthreads();
  float acc[NPB];
  const float bj = b[j];
#pragma unroll
  for (int p = 0; p < NPB; ++p) acc[p] = bj;
  for (int i = 0; i < FIN; i += 4) {    // 140 = 4*35
    const float w0 = w[(i + 0) * HID + j];
    const float w1 = w[(i + 1) * HID + j];
    const float w2 = w[(i + 2) * HID + j];
    const float w3 = w[(i + 3) * HID + j];
#pragma unroll
    for (int p = 0; p < NPB; ++p) {
      const float4 fv = *(const float4*)&fr[p * FIN + i];
      acc[p] = fmaf(fv.x, w0, acc[p]);
      acc[p] = fmaf(fv.y, w1, acc[p]);
      acc[p] = fmaf(fv.z, w2, acc[p]);
      acc[p] = fmaf(fv.w, w3, acc[p]);
    }
  }
#pragma unroll
  for (int p = 0; p < NPB; ++p)
    x[(size_t)(n0 + p) * HID + j] = fmaxf(acc[p], 0.f);
}

// h = x@W + b (stored bf16 for the gather); s_src/s_dst per head (from fp32 h)
__global__ __launch_bounds__(128) void proj_kernel(
    const float* __restrict__ x, const float* __restrict__ W,
    const float* __restrict__ b, const float* __restrict__ asrc,
    const float* __restrict__ adst, __hip_bfloat16* __restrict__ hbf,
    float* __restrict__ ssrc, float* __restrict__ sdst) {
  const int n0 = blockIdx.x * NPB;
  const int j = threadIdx.x;            // output column = head*16 + d
  __shared__ float xr[NPB * HID];
  const float* xbase = x + (size_t)n0 * HID;
  for (int t = j; t < NPB * HID; t += 128) xr[t] = xbase[t];
  __syncthreads();
  float acc[NPB];
  const float bj = b[j];
#pragma unroll
  for (int p = 0; p < NPB; ++p) acc[p] = bj;
  for (int i = 0; i < HID; i += 4) {
    const float w0 = W[(i + 0) * HID + j];
    const float w1 = W[(i + 1) * HID + j];
    const float w2 = W[(i + 2) * HID + j];
    const float w3 = W[(i + 3) * HID + j];
#pragma unroll
    for (int p = 0; p < NPB; ++p) {
      const float4 xv = *(const float4*)&xr[p * HID + i];
      acc[p] = fmaf(xv.x, w0, acc[p]);
      acc[p] = fmaf(xv.y, w1, acc[p]);
      acc[p] = fmaf(xv.z, w2, acc[p]);
      acc[p] = fmaf(xv.w, w3, acc[p]);
    }
  }
  const float av = asrc[j];
  const float dv = adst[j];
  const int head = j >> 4;              // d = j & 15
#pragma unroll
  for (int p = 0; p < NPB; ++p) {
    hbf[(size_t)(n0 + p) * HID + j] = __float2bfloat16(acc[p]);
    float vs = acc[p] * av;
    float vd = acc[p] * dv;
    vs += __shfl_xor(vs, 1, 16); vd += __shfl_xor(vd, 1, 16);
    vs += __shfl_xor(vs, 2, 16); vd += __shfl_xor(vd, 2, 16);
    vs += __shfl_xor(vs, 4, 16); vd += __shfl_xor(vd, 4, 16);
    vs += __shfl_xor(vs, 8, 16); vd += __shfl_xor(vd, 8, 16);
    if ((j & 15) == 0) {
      ssrc[(size_t)(n0 + p) * HH + head] = vs;
      sdst[(size_t)(n0 + p) * HH + head] = vd;
    }
  }
}

// one node per 64-thread wave: logits -> softmax over K -> bf16 gather agg -> ELU
__global__ __launch_bounds__(64) void attn_kernel(
    const int* __restrict__ nb, const unsigned int* __restrict__ hbf,
    const float* __restrict__ ssrc, const float* __restrict__ sdst,
    float* __restrict__ xout) {
  const int n = blockIdx.x;
  const int j = threadIdx.x;            // 0..63
  __shared__ int nbs[KK];
  __shared__ float aw[KK][HH];
  if (j < KK) nbs[j] = nb[(size_t)n * KK + j];
  __syncthreads();
  {
    // 128 (k,h) pairs over 64 threads: p = j and j+64
    const int k0 = j >> 3, h0 = j & 7;
    const int k1 = (j + 64) >> 3, h1 = h0;
    float e0 = ssrc[(size_t)n * HH + h0] + sdst[(size_t)nbs[k0] * HH + h0];
    float e1 = ssrc[(size_t)n * HH + h1] + sdst[(size_t)nbs[k1] * HH + h1];
    aw[k0][h0] = e0 > 0.f ? e0 : 0.2f * e0;
    aw[k1][h1] = e1 > 0.f ? e1 : 0.2f * e1;
  }
  __syncthreads();
  if (j < HH) {                         // softmax over K for head j
    float m = -1e30f;
#pragma unroll
    for (int k = 0; k < KK; ++k) m = fmaxf(m, aw[k][j]);
    float s = 0.f;
#pragma unroll
    for (int k = 0; k < KK; ++k) {
      const float v = __expf(aw[k][j] - m);
      aw[k][j] = v;
      s += v;
    }
    const float inv = 1.f / s;
#pragma unroll
    for (int k = 0; k < KK; ++k) aw[k][j] *= inv;
  }
  __syncthreads();
  // thread j covers columns 2j, 2j+1 (same head)
  const int head = j >> 3;
  float acc0 = 0.f, acc1 = 0.f;
#pragma unroll
  for (int k = 0; k < KK; ++k) {
    const unsigned int u = hbf[(size_t)nbs[k] * (HID / 2) + j];
    const float a = aw[k][head];
    acc0 = fmaf(a, __uint_as_float(u << 16), acc0);
    acc1 = fmaf(a, __uint_as_float(u & 0xffff0000u), acc1);
  }
  float2 o;
  o.x = acc0 > 0.f ? acc0 : expm1f(acc0);
  o.y = acc1 > 0.f ? acc1 : expm1f(acc1);
  *(float2*)&xout[(size_t)n * HID + 2 * j] = o;
}

extern "C" void kernel_launch(void* const* d_in, const int* in_sizes, int n_in,
                              void* d_out, int out_size, void* d_ws, size_t ws_size,
                              hipStream_t stream) {
  const float* feature = (const float*)d_in[0];
  const int*   nb      = (const int*)d_in[1];
  const float* pca_w   = (const float*)d_in[2];
  const float* pca_b   = (const float*)d_in[3];
  const float* Ws      = (const float*)d_in[4];
  const float* bs      = (const float*)d_in[5];
  const float* a_src   = (const float*)d_in[6];
  const float* a_dst   = (const float*)d_in[7];
  float* out = (float*)d_out;

  float* xbuf = (float*)d_ws;                               // [N,128] fp32
  __hip_bfloat16* hbf = (__hip_bfloat16*)(xbuf + (size_t)NN * HID);  // [N,128] bf16
  float* ssrc = (float*)(hbf + (size_t)NN * HID);           // [N,8]
  float* sdst = ssrc + (size_t)NN * HH;                     // [N,8]

  pca_kernel<<<NN / NPB, 128, 0, stream>>>(feature, pca_w, pca_b, xbuf);
  for (int l = 0; l < 2; ++l) {
    proj_kernel<<<NN / NPB, 128, 0, stream>>>(
        xbuf, Ws + (size_t)l * HID * HID, bs + (size_t)l * HID,
        a_src + (size_t)l * HID, a_dst + (size_t)l * HID, hbf, ssrc, sdst);
    attn_kernel<<<NN, 64, 0, stream>>>(nb, (const unsigned int*)hbf, ssrc, sdst,
                                       (l == 1) ? out : xbuf);
  }
}

// Round 3
// 214.946 us; speedup vs baseline: 1.5877x; 1.3234x over previous
//
#include <hip/hip_runtime.h>
#include <math.h>

#define NN 50000
#define KK 16
#define FIN 140
#define HH 8
#define HID 128

typedef __attribute__((ext_vector_type(8))) short short8;   // 8 bf16 = 4 VGPRs
typedef __attribute__((ext_vector_type(4))) float f32x4;    // MFMA acc

__device__ inline unsigned short f2bf(float f) {            // RNE fp32->bf16
  unsigned int u = __float_as_uint(f);
  return (unsigned short)((u + 0x7fffu + ((u >> 16) & 1u)) >> 16);
}
__device__ inline float bf2f(unsigned short h) {
  return __uint_as_float(((unsigned int)h) << 16);
}

// Build B-operand fragment tables (hi/lo bf16 split) for pca_w and both Ws.
// Fragment layout for mfma_f32_16x16x32_bf16 B: lane L holds B[k=(L>>4)*8+j][n=t*16+(L&15)],
// stored so lane L reads 8 contiguous shorts at ((c*8+t)*64+L)*8.
// frags layout (shorts): [pcaH 20480][pcaL 20480][W0H 16384][W0L 16384][W1H 16384][W1L 16384]
__global__ __launch_bounds__(256) void prep_kernel(
    const float* __restrict__ pca_w, const float* __restrict__ Ws,
    unsigned short* __restrict__ frags) {
  const int gid = blockIdx.x * 256 + threadIdx.x;   // 208*256 = 53248 exact
  const float* W; int K; unsigned short *dh, *dl; int tid;
  if (gid < 20480)      { W = pca_w;          K = FIN; dh = frags;                 dl = dh + 20480; tid = gid; }
  else if (gid < 36864) { W = Ws;             K = HID; dh = frags + 40960;         dl = dh + 16384; tid = gid - 20480; }
  else                  { W = Ws + HID * HID; K = HID; dh = frags + 40960 + 32768; dl = dh + 16384; tid = gid - 36864; }
  const int j = tid & 7, L = (tid >> 3) & 63, ct = tid >> 9, t = ct & 7, c = ct >> 3;
  const int k = c * 32 + (L >> 4) * 8 + j;
  const int col = t * 16 + (L & 15);
  const float v = (k < K) ? W[(size_t)k * HID + col] : 0.f;
  const unsigned short h = f2bf(v);
  dh[tid] = h;
  dl[tid] = f2bf(v - bf2f(h));
}

__device__ inline void split8(const float4& a0, const float4& a1, short8& Ah, short8& Al) {
  const float av[8] = {a0.x, a0.y, a0.z, a0.w, a1.x, a1.y, a1.z, a1.w};
#pragma unroll
  for (int j = 0; j < 8; ++j) {
    const unsigned short hb = f2bf(av[j]);
    Ah[j] = (short)hb;
    Al[j] = (short)f2bf(av[j] - bf2f(hb));
  }
}

// x = relu(feature @ pca_w + b), split-bf16 MFMA, K=140 padded to 160 (5 chunks)
__global__ __launch_bounds__(64) void pca_mfma(
    const float* __restrict__ feat, const unsigned short* __restrict__ wfh,
    const unsigned short* __restrict__ wfl, const float* __restrict__ b,
    float* __restrict__ x) {
  const int n0 = blockIdx.x * 16;
  const int lane = threadIdx.x;
  const int col = lane & 15, quad = lane >> 4;
  f32x4 acc[8];
#pragma unroll
  for (int t = 0; t < 8; ++t) acc[t] = (f32x4){0.f, 0.f, 0.f, 0.f};
  const float* arow = feat + (size_t)(n0 + col) * FIN + quad * 8;
#pragma unroll
  for (int c = 0; c < 5; ++c) {
    float4 a0, a1;
    if (c < 4) {
      a0 = *(const float4*)(arow + c * 32);
      a1 = *(const float4*)(arow + c * 32 + 4);
    } else {  // chunk 4: k = 128 + quad*8 + j, valid only k < 140
      a0 = make_float4(0.f, 0.f, 0.f, 0.f);
      a1 = make_float4(0.f, 0.f, 0.f, 0.f);
      if (quad == 0) { a0 = *(const float4*)(arow + 128); a1 = *(const float4*)(arow + 132); }
      else if (quad == 1) { a0 = *(const float4*)(arow + 128); }  // k=136..139
    }
    short8 Ah, Al;
    split8(a0, a1, Ah, Al);
#pragma unroll
    for (int t = 0; t < 8; ++t) {
      const short8 Bh = *(const short8*)(wfh + ((size_t)(c * 8 + t) * 64 + lane) * 8);
      const short8 Bl = *(const short8*)(wfl + ((size_t)(c * 8 + t) * 64 + lane) * 8);
      acc[t] = __builtin_amdgcn_mfma_f32_16x16x32_bf16(Ah, Bl, acc[t], 0, 0, 0);
      acc[t] = __builtin_amdgcn_mfma_f32_16x16x32_bf16(Al, Bh, acc[t], 0, 0, 0);
      acc[t] = __builtin_amdgcn_mfma_f32_16x16x32_bf16(Ah, Bh, acc[t], 0, 0, 0);
    }
  }
  // C/D layout: col = lane&15, row = quad*4 + r  [m89]
#pragma unroll
  for (int t = 0; t < 8; ++t) {
    const float bj = b[t * 16 + col];
#pragma unroll
    for (int r = 0; r < 4; ++r) {
      const float v = acc[t][r] + bj;
      x[(size_t)(n0 + quad * 4 + r) * HID + t * 16 + col] = fmaxf(v, 0.f);
    }
  }
}

// h = x@W + b (bf16 store); s_src/s_dst per head from fp32 h. Split-bf16 MFMA, K=128.
__global__ __launch_bounds__(64) void proj_mfma(
    const float* __restrict__ xin, const unsigned short* __restrict__ wfh,
    const unsigned short* __restrict__ wfl, const float* __restrict__ b,
    const float* __restrict__ asrc, const float* __restrict__ adst,
    unsigned short* __restrict__ hbf, float* __restrict__ ssrc,
    float* __restrict__ sdst) {
  const int n0 = blockIdx.x * 16;
  const int lane = threadIdx.x;
  const int col = lane & 15, quad = lane >> 4;
  f32x4 acc[8];
#pragma unroll
  for (int t = 0; t < 8; ++t) acc[t] = (f32x4){0.f, 0.f, 0.f, 0.f};
  const float* arow = xin + (size_t)(n0 + col) * HID + quad * 8;
#pragma unroll
  for (int c = 0; c < 4; ++c) {
    const float4 a0 = *(const float4*)(arow + c * 32);
    const float4 a1 = *(const float4*)(arow + c * 32 + 4);
    short8 Ah, Al;
    split8(a0, a1, Ah, Al);
#pragma unroll
    for (int t = 0; t < 8; ++t) {
      const short8 Bh = *(const short8*)(wfh + ((size_t)(c * 8 + t) * 64 + lane) * 8);
      const short8 Bl = *(const short8*)(wfl + ((size_t)(c * 8 + t) * 64 + lane) * 8);
      acc[t] = __builtin_amdgcn_mfma_f32_16x16x32_bf16(Ah, Bl, acc[t], 0, 0, 0);
      acc[t] = __builtin_amdgcn_mfma_f32_16x16x32_bf16(Al, Bh, acc[t], 0, 0, 0);
      acc[t] = __builtin_amdgcn_mfma_f32_16x16x32_bf16(Ah, Bh, acc[t], 0, 0, 0);
    }
  }
  // epilogue: bias, bf16 h store, per-head logits (head == tile t)
#pragma unroll
  for (int t = 0; t < 8; ++t) {
    const float bj = b[t * 16 + col];
    const float av = asrc[t * 16 + col];
    const float dv = adst[t * 16 + col];
#pragma unroll
    for (int r = 0; r < 4; ++r) {
      const float v = acc[t][r] + bj;
      const int row = n0 + quad * 4 + r;
      hbf[(size_t)row * HID + t * 16 + col] = f2bf(v);
      float vs = v * av;
      float vd = v * dv;
      vs += __shfl_xor(vs, 1, 16); vd += __shfl_xor(vd, 1, 16);
      vs += __shfl_xor(vs, 2, 16); vd += __shfl_xor(vd, 2, 16);
      vs += __shfl_xor(vs, 4, 16); vd += __shfl_xor(vd, 4, 16);
      vs += __shfl_xor(vs, 8, 16); vd += __shfl_xor(vd, 8, 16);
      if (col == 0) {
        ssrc[(size_t)row * HH + t] = vs;
        sdst[(size_t)row * HH + t] = vd;
      }
    }
  }
}

// one node per 64-thread wave: logits -> softmax over K -> bf16 gather agg -> ELU
__global__ __launch_bounds__(64) void attn_kernel(
    const int* __restrict__ nb, const unsigned int* __restrict__ hbf,
    const float* __restrict__ ssrc, const float* __restrict__ sdst,
    float* __restrict__ xout) {
  const int n = blockIdx.x;
  const int j = threadIdx.x;            // 0..63
  __shared__ int nbs[KK];
  __shared__ float aw[KK][HH];
  if (j < KK) nbs[j] = nb[(size_t)n * KK + j];
  __syncthreads();
  {
    const int k0 = j >> 3, h0 = j & 7;
    const int k1 = (j + 64) >> 3;
    float e0 = ssrc[(size_t)n * HH + h0] + sdst[(size_t)nbs[k0] * HH + h0];
    float e1 = ssrc[(size_t)n * HH + h0] + sdst[(size_t)nbs[k1] * HH + h0];
    aw[k0][h0] = e0 > 0.f ? e0 : 0.2f * e0;
    aw[k1][h0] = e1 > 0.f ? e1 : 0.2f * e1;
  }
  __syncthreads();
  if (j < HH) {                         // softmax over K for head j
    float m = -1e30f;
#pragma unroll
    for (int k = 0; k < KK; ++k) m = fmaxf(m, aw[k][j]);
    float s = 0.f;
#pragma unroll
    for (int k = 0; k < KK; ++k) {
      const float v = __expf(aw[k][j] - m);
      aw[k][j] = v;
      s += v;
    }
    const float inv = 1.f / s;
#pragma unroll
    for (int k = 0; k < KK; ++k) aw[k][j] *= inv;
  }
  __syncthreads();
  // thread j covers columns 2j, 2j+1 (same head)
  const int head = j >> 3;
  float acc0 = 0.f, acc1 = 0.f;
#pragma unroll
  for (int k = 0; k < KK; ++k) {
    const unsigned int u = hbf[(size_t)nbs[k] * (HID / 2) + j];
    const float a = aw[k][head];
    acc0 = fmaf(a, __uint_as_float(u << 16), acc0);
    acc1 = fmaf(a, __uint_as_float(u & 0xffff0000u), acc1);
  }
  float2 o;
  o.x = acc0 > 0.f ? acc0 : expm1f(acc0);
  o.y = acc1 > 0.f ? acc1 : expm1f(acc1);
  *(float2*)&xout[(size_t)n * HID + 2 * j] = o;
}

extern "C" void kernel_launch(void* const* d_in, const int* in_sizes, int n_in,
                              void* d_out, int out_size, void* d_ws, size_t ws_size,
                              hipStream_t stream) {
  const float* feature = (const float*)d_in[0];
  const int*   nb      = (const int*)d_in[1];
  const float* pca_w   = (const float*)d_in[2];
  const float* pca_b   = (const float*)d_in[3];
  const float* Ws      = (const float*)d_in[4];
  const float* bs      = (const float*)d_in[5];
  const float* a_src   = (const float*)d_in[6];
  const float* a_dst   = (const float*)d_in[7];
  float* out = (float*)d_out;

  float* xbuf = (float*)d_ws;                                        // [N,128] fp32
  unsigned short* hbf = (unsigned short*)(xbuf + (size_t)NN * HID);  // [N,128] bf16
  float* ssrc = (float*)(hbf + (size_t)NN * HID);                    // [N,8]
  float* sdst = ssrc + (size_t)NN * HH;                              // [N,8]
  unsigned short* frags = (unsigned short*)(sdst + (size_t)NN * HH); // 106496 shorts

  prep_kernel<<<208, 256, 0, stream>>>(pca_w, Ws, frags);
  pca_mfma<<<NN / 16, 64, 0, stream>>>(feature, frags, frags + 20480, pca_b, xbuf);
  for (int l = 0; l < 2; ++l) {
    const unsigned short* wh = frags + 40960 + (size_t)l * 32768;
    proj_mfma<<<NN / 16, 64, 0, stream>>>(
        xbuf, wh, wh + 16384, bs + (size_t)l * HID,
        a_src + (size_t)l * HID, a_dst + (size_t)l * HID, hbf, ssrc, sdst);
    attn_kernel<<<NN, 64, 0, stream>>>(nb, (const unsigned int*)hbf, ssrc, sdst,
                                       (l == 1) ? out : xbuf);
  }
}